// Round 7
// baseline (547.786 us; speedup 1.0000x reference)
//
#include <hip/hip_runtime.h>
#include <hip/hip_cooperative_groups.h>
#include <math.h>

namespace cg = cooperative_groups;

#define NB 8
#define N_SRC 2048
#define N_DST 8192
#define C_SRC 128
#define C_SKIP 64
#define C_IN 192
#define C_H 128
#define N_ROWS (NB * N_DST)   /* 65536 */
#define BN_EPS 1e-5f
#define SLOPE 0.01f
#define GEMM_BLOCKS (N_ROWS / 64)   /* 1024 (fallback) */
#define GRID_COOP 512               /* coop: 2 tiles of 64 rows per block */

using short8 = __attribute__((ext_vector_type(8))) short;
using f32x4  = __attribute__((ext_vector_type(4))) float;
using sf16   = __attribute__((ext_vector_type(16))) float;

static __device__ __forceinline__ unsigned short f2bf(float f) {
    unsigned u = __builtin_bit_cast(unsigned, f);
    u = u + 0x7FFFu + ((u >> 16) & 1u);   // round-to-nearest-even
    return (unsigned short)(u >> 16);
}

// ---------------------------------------------------------------------------
// Prep: W1,W2 fp32 -> bf16 ([out][in] K-contiguous); pos -> float4 array.
// ---------------------------------------------------------------------------
__global__ __launch_bounds__(256) void k_prep(const float* __restrict__ W1,
                                              unsigned short* __restrict__ W1bf,
                                              const float* __restrict__ W2,
                                              unsigned short* __restrict__ W2bf,
                                              const float* __restrict__ pos,
                                              float4* __restrict__ pos4) {
    int gid = blockIdx.x * 256 + threadIdx.x;
    int stride = gridDim.x * 256;
    for (int i = gid; i < C_H * C_IN; i += stride) W1bf[i] = f2bf(W1[i]);
    for (int i = gid; i < C_H * C_H; i += stride)  W2bf[i] = f2bf(W2[i]);
    for (int p = gid; p < NB * N_SRC; p += stride) {
        pos4[p] = make_float4(pos[p * 3 + 0], pos[p * 3 + 1], pos[p * 3 + 2], 0.f);
    }
}

// ===========================================================================
// COOPERATIVE PATH: one persistent kernel, 512 blocks x 2 tiles.
// ===========================================================================
__global__ __launch_bounds__(256, 2) void k_coop(
    const float4* __restrict__ pos4, const float* __restrict__ pos_skip,
    const float* __restrict__ x, const float* __restrict__ x_skip,
    const unsigned short* __restrict__ W1bf, const float* __restrict__ b1,
    const float* __restrict__ g1, const float* __restrict__ be1,
    const unsigned short* __restrict__ W2bf, const float* __restrict__ b2,
    const float* __restrict__ g2, const float* __restrict__ be2,
    const int* __restrict__ batch_skip,
    float* __restrict__ out_h, float* __restrict__ out_pos,
    float* __restrict__ out_batch,
    float* __restrict__ p1s, float* __restrict__ p1q,
    float* __restrict__ p2s, float* __restrict__ p2q,
    float* __restrict__ a1g, float* __restrict__ c1g,
    float* __restrict__ a2g, float* __restrict__ c2g)
{
    cg::grid_group grid = cg::this_grid();

    __shared__ __align__(16) unsigned short AshMem[64 * 200];  // 25600 B
    __shared__ float sS[4][128];
    __shared__ float sQ[4][128];
    __shared__ float cdA[2][4][64][3];
    __shared__ int   ciA[2][4][64][3];
    __shared__ int   midx[2][64][3];
    __shared__ float mw[2][64][3];
    __shared__ float rsm[4], rqm[4];

    int tid = threadIdx.x;
    int l = tid & 63, w = tid >> 6;
    int blk = blockIdx.x;
    int cloud = blk >> 6;          // 64 blocks (128 rows each) per cloud
    int r0 = blk * 128;

    // ---- pos/batch copy for this block's 128 rows ----
    for (int i = tid; i < 384; i += 256)
        out_pos[(size_t)r0 * 3 + i] = pos_skip[(size_t)r0 * 3 + i];
    if (tid < 128) out_batch[r0 + tid] = (float)batch_skip[r0 + tid];

    // ---------------- Phase A: dual-tile KNN scan ----------------
    int dAi = (r0 + l) * 3, dBi = (r0 + 64 + l) * 3;
    float pxA = pos_skip[dAi], pyA = pos_skip[dAi + 1], pzA = pos_skip[dAi + 2];
    float pxB = pos_skip[dBi], pyB = pos_skip[dBi + 1], pzB = pos_skip[dBi + 2];

    const float4* __restrict__ pw = pos4 + (cloud << 11) + (w << 9);
    float4 C[8];
#pragma unroll
    for (int c = 0; c < 8; ++c) C[c] = pw[c * 64 + l];

    float ra0 = 3.4e38f, ra1 = 3.4e38f, ra2 = 3.4e38f;
    int   ia0 = 0, ia1 = 0, ia2 = 0;
    float rb0 = 3.4e38f, rb1 = 3.4e38f, rb2 = 3.4e38f;
    int   ib0 = 0, ib1 = 0, ib2 = 0;
#pragma unroll
    for (int c = 0; c < 8; ++c) {
        int jb = (w << 9) + c * 64;
        int vx = __float_as_int(C[c].x);
        int vy = __float_as_int(C[c].y);
        int vz = __float_as_int(C[c].z);
#pragma unroll 2
        for (int k = 0; k < 64; ++k) {
            float sx = __int_as_float(__builtin_amdgcn_readlane(vx, k));
            float sy = __int_as_float(__builtin_amdgcn_readlane(vy, k));
            float sz = __int_as_float(__builtin_amdgcn_readlane(vz, k));
            float dxA = pxA - sx, dyA = pyA - sy, dzA = pzA - sz;
            float dA = fmaf(dxA, dxA, fmaf(dyA, dyA, dzA * dzA));
            float dxB = pxB - sx, dyB = pyB - sy, dzB = pzB - sz;
            float dB = fmaf(dxB, dxB, fmaf(dyB, dyB, dzB * dzB));
            if (dA < ra2) {
                int jj = jb + k;
                bool c0 = dA < ra0, c1 = dA < ra1;
                ia2 = c1 ? ia1 : jj;            ra2 = c1 ? ra1 : dA;
                ia1 = c1 ? (c0 ? ia0 : jj) : ia1; ra1 = c1 ? (c0 ? ra0 : dA) : ra1;
                ia0 = c0 ? jj : ia0;            ra0 = c0 ? dA : ra0;
            }
            if (dB < rb2) {
                int jj = jb + k;
                bool c0 = dB < rb0, c1 = dB < rb1;
                ib2 = c1 ? ib1 : jj;            rb2 = c1 ? rb1 : dB;
                ib1 = c1 ? (c0 ? ib0 : jj) : ib1; rb1 = c1 ? (c0 ? rb0 : dB) : rb1;
                ib0 = c0 ? jj : ib0;            rb0 = c0 ? dB : rb0;
            }
        }
    }
    cdA[0][w][l][0] = ra0; cdA[0][w][l][1] = ra1; cdA[0][w][l][2] = ra2;
    ciA[0][w][l][0] = ia0; ciA[0][w][l][1] = ia1; ciA[0][w][l][2] = ia2;
    cdA[1][w][l][0] = rb0; cdA[1][w][l][1] = rb1; cdA[1][w][l][2] = rb2;
    ciA[1][w][l][0] = ib0; ciA[1][w][l][1] = ib1; ciA[1][w][l][2] = ib2;
    __syncthreads();

    // ---------------- merge 12 candidates per dst (both tiles in parallel) --
    if (tid < 128) {
        int t = tid >> 6, q = tid & 63;
        float e0 = 3.4e38f, e1 = 3.4e38f, e2 = 3.4e38f;
        int   m0 = 0, m1 = 0, m2 = 0;
#pragma unroll
        for (int s = 0; s < 4; ++s) {
#pragma unroll
            for (int rk = 0; rk < 3; ++rk) {
                float d = cdA[t][s][q][rk];
                int  jj = ciA[t][s][q][rk];
                if (d < e2) {
                    bool c0 = d < e0, c1 = d < e1;
                    m2 = c1 ? m1 : jj;            e2 = c1 ? e1 : d;
                    m1 = c1 ? (c0 ? m0 : jj) : m1; e1 = c1 ? (c0 ? e0 : d) : e1;
                    m0 = c0 ? jj : m0;            e0 = c0 ? d : e0;
                }
            }
        }
        float w0 = 1.f / fmaxf(e0, 1e-16f);
        float w1 = 1.f / fmaxf(e1, 1e-16f);
        float w2 = 1.f / fmaxf(e2, 1e-16f);
        float inv = 1.f / (w0 + w1 + w2);
        midx[t][q][0] = m0; midx[t][q][1] = m1; midx[t][q][2] = m2;
        mw[t][q][0] = w0 * inv; mw[t][q][1] = w1 * inv; mw[t][q][2] = w2 * inv;
    }
    __syncthreads();

    // ---------------- Phase B: per tile, gather -> MFMA1 -> lrelu -> partials
    int cl = l & 15, kh = l >> 4;
    const float* xb = x + (size_t)cloud * N_SRC * C_SRC;
    f32x4 acc[2][8];

#pragma unroll
    for (int t = 0; t < 2; ++t) {
        int r0t = r0 + t * 64;
        for (int rr = w * 16; rr < w * 16 + 16; ++rr) {
            int j0 = midx[t][rr][0], j1 = midx[t][rr][1], j2 = midx[t][rr][2];
            float w0 = mw[t][rr][0], w1 = mw[t][rr][1], w2 = mw[t][rr][2];
            const float2* x0v = (const float2*)(xb + (size_t)j0 * C_SRC);
            const float2* x1v = (const float2*)(xb + (size_t)j1 * C_SRC);
            const float2* x2v = (const float2*)(xb + (size_t)j2 * C_SRC);
            float2 a = x0v[l], b = x1v[l], c = x2v[l];
            float v0 = w0 * a.x + w1 * b.x + w2 * c.x;
            float v1 = w0 * a.y + w1 * b.y + w2 * c.y;
            ((unsigned*)&AshMem[rr * 200])[l] =
                (unsigned)f2bf(v0) | ((unsigned)f2bf(v1) << 16);
            AshMem[rr * 200 + 128 + l] =
                f2bf(x_skip[(size_t)(r0t + rr) * C_SKIP + l]);
        }
        // wave writes & reads only its own 16-row slab -> no barrier

#pragma unroll
        for (int n = 0; n < 8; ++n) {
            float bv = b1[n * 16 + cl];
            acc[t][n][0] = bv; acc[t][n][1] = bv;
            acc[t][n][2] = bv; acc[t][n][3] = bv;
        }
        const unsigned short* wb = W1bf + (size_t)cl * C_IN + kh * 8;
        for (int kt = 0; kt < 6; ++kt) {
            short8 af = *(const short8*)&AshMem[(w * 16 + cl) * 200 + kt * 32 + kh * 8];
#pragma unroll
            for (int n = 0; n < 8; ++n) {
                short8 bf = *(const short8*)(wb + (size_t)n * 16 * C_IN + kt * 32);
                acc[t][n] = __builtin_amdgcn_mfma_f32_16x16x32_bf16(af, bf, acc[t][n], 0, 0, 0);
            }
        }

#pragma unroll
        for (int n = 0; n < 8; ++n) {
            float s = 0.f, q = 0.f;
#pragma unroll
            for (int j = 0; j < 4; ++j) {
                float z = acc[t][n][j];
                z = z > 0.f ? z : SLOPE * z;
                acc[t][n][j] = z;                 // h1 kept in regs
                s += z; q += z * z;
            }
            s += __shfl_xor(s, 16); s += __shfl_xor(s, 32);
            q += __shfl_xor(q, 16); q += __shfl_xor(q, 32);
            if (l < 16) {
                if (t == 0) { sS[w][n * 16 + l] = s;  sQ[w][n * 16 + l] = q; }
                else        { sS[w][n * 16 + l] += s; sQ[w][n * 16 + l] += q; }
            }
        }
    }
    __syncthreads();
    if (tid < 128) {
        float s = sS[0][tid] + sS[1][tid] + sS[2][tid] + sS[3][tid];
        float q = sQ[0][tid] + sQ[1][tid] + sQ[2][tid] + sQ[3][tid];
        p1s[(size_t)tid * GRID_COOP + blk] = s;
        p1q[(size_t)tid * GRID_COOP + blk] = q;
    }

    __threadfence();
    grid.sync();                                    // ---- sync #1 ----

    if (blk < C_H) {
        int col = blk;
        float s = 0.f, q = 0.f;
        for (int b = tid; b < GRID_COOP; b += 256) {
            s += p1s[(size_t)col * GRID_COOP + b];
            q += p1q[(size_t)col * GRID_COOP + b];
        }
        for (int off = 32; off; off >>= 1) {
            s += __shfl_down(s, off);
            q += __shfl_down(q, off);
        }
        if ((tid & 63) == 0) { rsm[tid >> 6] = s; rqm[tid >> 6] = q; }
        __syncthreads();
        if (tid == 0) {
            s = rsm[0] + rsm[1] + rsm[2] + rsm[3];
            q = rqm[0] + rqm[1] + rqm[2] + rqm[3];
            float mean = s / (float)N_ROWS;
            float var  = q / (float)N_ROWS - mean * mean;
            float a = g1[col] * rsqrtf(var + BN_EPS);
            a1g[col] = a;
            c1g[col] = be1[col] - mean * a;
        }
    }

    __threadfence();
    grid.sync();                                    // ---- sync #2 ----

    // ---------------- Phase C: per tile, BN1 -> MFMA2 -> lrelu -> partials --
    f32x4 acc2[2][8];
#pragma unroll
    for (int t = 0; t < 2; ++t) {
#pragma unroll
        for (int n = 0; n < 8; ++n) {
            int col = n * 16 + cl;
            float av = a1g[col], cv = c1g[col];
#pragma unroll
            for (int j = 0; j < 4; ++j) {
                int row = w * 16 + kh * 4 + j;
                AshMem[row * 136 + col] = f2bf(fmaf(av, acc[t][n][j], cv));
            }
        }
        // own-slab write/read -> no barrier

#pragma unroll
        for (int n = 0; n < 8; ++n) {
            float bv = b2[n * 16 + cl];
            acc2[t][n][0] = bv; acc2[t][n][1] = bv;
            acc2[t][n][2] = bv; acc2[t][n][3] = bv;
        }
        const unsigned short* wb = W2bf + (size_t)cl * C_H + kh * 8;
        for (int kt = 0; kt < 4; ++kt) {
            short8 af = *(const short8*)&AshMem[(w * 16 + cl) * 136 + kt * 32 + kh * 8];
#pragma unroll
            for (int n = 0; n < 8; ++n) {
                short8 bf = *(const short8*)(wb + (size_t)n * 16 * C_H + kt * 32);
                acc2[t][n] = __builtin_amdgcn_mfma_f32_16x16x32_bf16(af, bf, acc2[t][n], 0, 0, 0);
            }
        }

#pragma unroll
        for (int n = 0; n < 8; ++n) {
            float s = 0.f, q = 0.f;
#pragma unroll
            for (int j = 0; j < 4; ++j) {
                float z = acc2[t][n][j];
                z = z > 0.f ? z : SLOPE * z;
                acc2[t][n][j] = z;
                s += z; q += z * z;
            }
            s += __shfl_xor(s, 16); s += __shfl_xor(s, 32);
            q += __shfl_xor(q, 16); q += __shfl_xor(q, 32);
            if (l < 16) {
                if (t == 0) { sS[w][n * 16 + l] = s;  sQ[w][n * 16 + l] = q; }
                else        { sS[w][n * 16 + l] += s; sQ[w][n * 16 + l] += q; }
            }
        }
    }
    __syncthreads();
    if (tid < 128) {
        float s = sS[0][tid] + sS[1][tid] + sS[2][tid] + sS[3][tid];
        float q = sQ[0][tid] + sQ[1][tid] + sQ[2][tid] + sQ[3][tid];
        p2s[(size_t)tid * GRID_COOP + blk] = s;
        p2q[(size_t)tid * GRID_COOP + blk] = q;
    }

    __threadfence();
    grid.sync();                                    // ---- sync #3 ----

    if (blk < C_H) {
        int col = blk;
        float s = 0.f, q = 0.f;
        for (int b = tid; b < GRID_COOP; b += 256) {
            s += p2s[(size_t)col * GRID_COOP + b];
            q += p2q[(size_t)col * GRID_COOP + b];
        }
        for (int off = 32; off; off >>= 1) {
            s += __shfl_down(s, off);
            q += __shfl_down(q, off);
        }
        if ((tid & 63) == 0) { rsm[tid >> 6] = s; rqm[tid >> 6] = q; }
        __syncthreads();
        if (tid == 0) {
            s = rsm[0] + rsm[1] + rsm[2] + rsm[3];
            q = rqm[0] + rqm[1] + rqm[2] + rqm[3];
            float mean = s / (float)N_ROWS;
            float var  = q / (float)N_ROWS - mean * mean;
            float a = g2[col] * rsqrtf(var + BN_EPS);
            a2g[col] = a;
            c2g[col] = be2[col] - mean * a;
        }
    }

    __threadfence();
    grid.sync();                                    // ---- sync #4 ----

    // ---------------- final: BN2 affine + store ----------------
#pragma unroll
    for (int t = 0; t < 2; ++t) {
#pragma unroll
        for (int n = 0; n < 8; ++n) {
            int col = n * 16 + cl;
            float av = a2g[col], cv = c2g[col];
#pragma unroll
            for (int j = 0; j < 4; ++j) {
                int row = r0 + t * 64 + w * 16 + kh * 4 + j;
                out_h[(size_t)row * C_H + col] = fmaf(av, acc2[t][n][j], cv);
            }
        }
    }
}

// ===========================================================================
// FALLBACK PATH: verified r5 pipeline (used only if coop launch fails).
// ===========================================================================
__global__ __launch_bounds__(256) void k_fused1(const float4* __restrict__ pos4,
                                                const float* __restrict__ pos_skip,
                                                const float* __restrict__ x,
                                                const float* __restrict__ x_skip,
                                                const unsigned short* __restrict__ Wbf,
                                                const float* __restrict__ bias,
                                                float* __restrict__ out,
                                                float* __restrict__ ps,
                                                float* __restrict__ pq) {
    __shared__ __align__(16) unsigned short Ash[64][200];
    __shared__ float sS[4][128];
    __shared__ float sQ[4][128];
    __shared__ int   midx[64][3];
    __shared__ float mw[64][3];

    float* cd = (float*)&Ash[0][0];
    int*   ci = (int*)((char*)&Ash[0][0] + 3072);

    int tid = threadIdx.x;
    int l = tid & 63;
    int w = __builtin_amdgcn_readfirstlane(tid >> 6);
    int cloud = blockIdx.x >> 7;
    int r0 = blockIdx.x * 64;

    int dst = r0 + l;
    float px = pos_skip[dst * 3 + 0];
    float py = pos_skip[dst * 3 + 1];
    float pz = pos_skip[dst * 3 + 2];

    float rr0 = 3.4e38f, rr1 = 3.4e38f, rr2 = 3.4e38f;
    int   ii0 = 0, ii1 = 0, ii2 = 0;

    const char* sp = (const char*)(pos4 + (cloud << 11) + (w << 9));
    for (int g = 0; g < 64; ++g) {
        sf16 A, B;
        asm volatile("s_load_dwordx16 %0, %2, 0x0\n\t"
                     "s_load_dwordx16 %1, %2, 0x40\n\t"
                     "s_waitcnt lgkmcnt(0)"
                     : "=s"(A), "=s"(B)
                     : "s"(sp));
        sp += 128;
        int jb = (w << 9) + g * 8;
#pragma unroll
        for (int k = 0; k < 4; ++k) {
            float dx = px - A[4 * k], dy = py - A[4 * k + 1], dz = pz - A[4 * k + 2];
            float d = fmaf(dx, dx, fmaf(dy, dy, dz * dz));
            if (d < rr2) {
                int jj = jb + k;
                bool c0 = d < rr0, c1 = d < rr1;
                ii2 = c1 ? ii1 : jj;            rr2 = c1 ? rr1 : d;
                ii1 = c1 ? (c0 ? ii0 : jj) : ii1; rr1 = c1 ? (c0 ? rr0 : d) : rr1;
                ii0 = c0 ? jj : ii0;            rr0 = c0 ? d : rr0;
            }
        }
#pragma unroll
        for (int k = 0; k < 4; ++k) {
            float dx = px - B[4 * k], dy = py - B[4 * k + 1], dz = pz - B[4 * k + 2];
            float d = fmaf(dx, dx, fmaf(dy, dy, dz * dz));
            if (d < rr2) {
                int jj = jb + 4 + k;
                bool c0 = d < rr0, c1 = d < rr1;
                ii2 = c1 ? ii1 : jj;            rr2 = c1 ? rr1 : d;
                ii1 = c1 ? (c0 ? ii0 : jj) : ii1; rr1 = c1 ? (c0 ? rr0 : d) : rr1;
                ii0 = c0 ? jj : ii0;            rr0 = c0 ? d : rr0;
            }
        }
    }
    cd[(w * 64 + l) * 3 + 0] = rr0; ci[(w * 64 + l) * 3 + 0] = ii0;
    cd[(w * 64 + l) * 3 + 1] = rr1; ci[(w * 64 + l) * 3 + 1] = ii1;
    cd[(w * 64 + l) * 3 + 2] = rr2; ci[(w * 64 + l) * 3 + 2] = ii2;
    __syncthreads();

    if (tid < 64) {
        float e0 = 3.4e38f, e1 = 3.4e38f, e2 = 3.4e38f;
        int   m0 = 0, m1 = 0, m2 = 0;
#pragma unroll
        for (int s = 0; s < 4; ++s) {
#pragma unroll
            for (int t = 0; t < 3; ++t) {
                float d = cd[(s * 64 + tid) * 3 + t];
                int  jj = ci[(s * 64 + tid) * 3 + t];
                if (d < e2) {
                    bool c0 = d < e0, c1 = d < e1;
                    m2 = c1 ? m1 : jj;            e2 = c1 ? e1 : d;
                    m1 = c1 ? (c0 ? m0 : jj) : m1; e1 = c1 ? (c0 ? e0 : d) : e1;
                    m0 = c0 ? jj : m0;            e0 = c0 ? d : e0;
                }
            }
        }
        float w0 = 1.f / fmaxf(e0, 1e-16f);
        float w1 = 1.f / fmaxf(e1, 1e-16f);
        float w2 = 1.f / fmaxf(e2, 1e-16f);
        float inv = 1.f / (w0 + w1 + w2);
        midx[tid][0] = m0; midx[tid][1] = m1; midx[tid][2] = m2;
        mw[tid][0] = w0 * inv; mw[tid][1] = w1 * inv; mw[tid][2] = w2 * inv;
    }
    __syncthreads();

    const float* xb = x + (size_t)cloud * N_SRC * C_SRC;
    for (int rr = w * 16; rr < w * 16 + 16; ++rr) {
        int j0 = midx[rr][0], j1 = midx[rr][1], j2 = midx[rr][2];
        float w0 = mw[rr][0], w1 = mw[rr][1], w2 = mw[rr][2];
        const float2* x0v = (const float2*)(xb + (size_t)j0 * C_SRC);
        const float2* x1v = (const float2*)(xb + (size_t)j1 * C_SRC);
        const float2* x2v = (const float2*)(xb + (size_t)j2 * C_SRC);
        float2 a = x0v[l], b = x1v[l], c = x2v[l];
        float v0 = w0 * a.x + w1 * b.x + w2 * c.x;
        float v1 = w0 * a.y + w1 * b.y + w2 * c.y;
        ((unsigned*)&Ash[rr][0])[l] = (unsigned)f2bf(v0) | ((unsigned)f2bf(v1) << 16);
        Ash[rr][128 + l] = f2bf(x_skip[(size_t)(r0 + rr) * C_SKIP + l]);
    }

    int cl = l & 15, kh = l >> 4;
    f32x4 acc[8];
#pragma unroll
    for (int n = 0; n < 8; ++n) {
        float bv = bias[n * 16 + cl];
        acc[n][0] = bv; acc[n][1] = bv; acc[n][2] = bv; acc[n][3] = bv;
    }
    const unsigned short* wb = Wbf + (size_t)cl * C_IN + kh * 8;
    for (int kt = 0; kt < 6; ++kt) {
        short8 af = *(const short8*)&Ash[w * 16 + cl][kt * 32 + kh * 8];
#pragma unroll
        for (int n = 0; n < 8; ++n) {
            short8 bf = *(const short8*)(wb + (size_t)n * 16 * C_IN + kt * 32);
            acc[n] = __builtin_amdgcn_mfma_f32_16x16x32_bf16(af, bf, acc[n], 0, 0, 0);
        }
    }

    float pss[8], pqs[8];
#pragma unroll
    for (int n = 0; n < 8; ++n) {
        float s = 0.f, q = 0.f;
        int col = n * 16 + cl;
#pragma unroll
        for (int j = 0; j < 4; ++j) {
            int row = r0 + w * 16 + kh * 4 + j;
            float z = acc[n][j];
            z = z > 0.f ? z : SLOPE * z;
            out[(size_t)row * C_H + col] = z;
            s += z; q += z * z;
        }
        s += __shfl_xor(s, 16); s += __shfl_xor(s, 32);
        q += __shfl_xor(q, 16); q += __shfl_xor(q, 32);
        pss[n] = s; pqs[n] = q;
    }
    if (l < 16) {
#pragma unroll
        for (int n = 0; n < 8; ++n) {
            sS[w][n * 16 + l] = pss[n];
            sQ[w][n * 16 + l] = pqs[n];
        }
    }
    __syncthreads();
    if (tid < 128) {
        float s = sS[0][tid] + sS[1][tid] + sS[2][tid] + sS[3][tid];
        float q = sQ[0][tid] + sQ[1][tid] + sQ[2][tid] + sQ[3][tid];
        ps[blockIdx.x * C_H + tid] = s;
        pq[blockIdx.x * C_H + tid] = q;
    }
}

__global__ __launch_bounds__(256) void k_reduce(const float* __restrict__ ps,
                                                const float* __restrict__ pq,
                                                const float* __restrict__ g,
                                                const float* __restrict__ be,
                                                float* __restrict__ a_out,
                                                float* __restrict__ c_out) {
    int col = blockIdx.x;
    float s = 0.f, q = 0.f;
    for (int b = threadIdx.x; b < GEMM_BLOCKS; b += 256) {
        s += ps[b * C_H + col];
        q += pq[b * C_H + col];
    }
    for (int off = 32; off; off >>= 1) {
        s += __shfl_down(s, off);
        q += __shfl_down(q, off);
    }
    __shared__ float rs[4], rq[4];
    if ((threadIdx.x & 63) == 0) { rs[threadIdx.x >> 6] = s; rq[threadIdx.x >> 6] = q; }
    __syncthreads();
    if (threadIdx.x == 0) {
        s = rs[0] + rs[1] + rs[2] + rs[3];
        q = rq[0] + rq[1] + rq[2] + rq[3];
        float mean = s / (float)N_ROWS;
        float var  = q / (float)N_ROWS - mean * mean;
        float a = g[col] * rsqrtf(var + BN_EPS);
        a_out[col] = a;
        c_out[col] = be[col] - mean * a;
    }
}

__global__ __launch_bounds__(256) void k_g2a(const float* __restrict__ h,
                                             const unsigned short* __restrict__ Wbf,
                                             const float* __restrict__ b2,
                                             const float* __restrict__ a1,
                                             const float* __restrict__ c1,
                                             float* __restrict__ ps,
                                             float* __restrict__ pq) {
    __shared__ __align__(16) unsigned short Ash[64][136];
    __shared__ float sS[4][128];
    __shared__ float sQ[4][128];

    int r0 = blockIdx.x * 64;
    int tid = threadIdx.x;
    int l = tid & 63, w = tid >> 6;

    const float* src = h + (size_t)r0 * C_H;
    for (int i = tid * 4; i < 64 * C_H; i += 1024) {
        float4 v = *(const float4*)&src[i];
        int r = i >> 7, c = i & 127;
        float4 av = *(const float4*)&a1[c];
        float4 cv = *(const float4*)&c1[c];
        unsigned lo = (unsigned)f2bf(fmaf(av.x, v.x, cv.x)) |
                      ((unsigned)f2bf(fmaf(av.y, v.y, cv.y)) << 16);
        unsigned hi = (unsigned)f2bf(fmaf(av.z, v.z, cv.z)) |
                      ((unsigned)f2bf(fmaf(av.w, v.w, cv.w)) << 16);
        *(uint2*)&Ash[r][c] = make_uint2(lo, hi);
    }
    __syncthreads();

    int cl = l & 15, kh = l >> 4;
    f32x4 acc[8];
#pragma unroll
    for (int n = 0; n < 8; ++n) {
        float bv = b2[n * 16 + cl];
        acc[n][0] = bv; acc[n][1] = bv; acc[n][2] = bv; acc[n][3] = bv;
    }
    const unsigned short* wb = Wbf + (size_t)cl * C_H + kh * 8;
    for (int kt = 0; kt < 4; ++kt) {
        short8 af = *(const short8*)&Ash[w * 16 + cl][kt * 32 + kh * 8];
#pragma unroll
        for (int n = 0; n < 8; ++n) {
            short8 bf = *(const short8*)(wb + (size_t)n * 16 * C_H + kt * 32);
            acc[n] = __builtin_amdgcn_mfma_f32_16x16x32_bf16(af, bf, acc[n], 0, 0, 0);
        }
    }

    float pss[8], pqs[8];
#pragma unroll
    for (int n = 0; n < 8; ++n) {
        float s = 0.f, q = 0.f;
#pragma unroll
        for (int j = 0; j < 4; ++j) {
            float z = acc[n][j];
            z = z > 0.f ? z : SLOPE * z;
            s += z; q += z * z;
        }
        s += __shfl_xor(s, 16); s += __shfl_xor(s, 32);
        q += __shfl_xor(q, 16); q += __shfl_xor(q, 32);
        pss[n] = s; pqs[n] = q;
    }
    if (l < 16) {
#pragma unroll
        for (int n = 0; n < 8; ++n) {
            sS[w][n * 16 + l] = pss[n];
            sQ[w][n * 16 + l] = pqs[n];
        }
    }
    __syncthreads();
    if (tid < 128) {
        float s = sS[0][tid] + sS[1][tid] + sS[2][tid] + sS[3][tid];
        float q = sQ[0][tid] + sQ[1][tid] + sQ[2][tid] + sQ[3][tid];
        ps[blockIdx.x * C_H + tid] = s;
        pq[blockIdx.x * C_H + tid] = q;
    }
}

__global__ __launch_bounds__(256) void k_g2b(float* __restrict__ h,
                                             const unsigned short* __restrict__ Wbf,
                                             const float* __restrict__ b2,
                                             const float* __restrict__ a1,
                                             const float* __restrict__ c1,
                                             const float* __restrict__ a2,
                                             const float* __restrict__ c2,
                                             const float* __restrict__ pos_skip,
                                             const int* __restrict__ batch_skip,
                                             float* __restrict__ out_pos,
                                             float* __restrict__ out_batch) {
    __shared__ __align__(16) unsigned short Ash[64][136];

    int r0 = blockIdx.x * 64;
    int tid = threadIdx.x;
    int l = tid & 63, w = tid >> 6;

    if (tid < 192) out_pos[(size_t)r0 * 3 + tid] = pos_skip[(size_t)r0 * 3 + tid];
    if (tid < 64)  out_batch[r0 + tid] = (float)batch_skip[r0 + tid];

    const float* src = h + (size_t)r0 * C_H;
    for (int i = tid * 4; i < 64 * C_H; i += 1024) {
        float4 v = *(const float4*)&src[i];
        int r = i >> 7, c = i & 127;
        float4 av = *(const float4*)&a1[c];
        float4 cv = *(const float4*)&c1[c];
        unsigned lo = (unsigned)f2bf(fmaf(av.x, v.x, cv.x)) |
                      ((unsigned)f2bf(fmaf(av.y, v.y, cv.y)) << 16);
        unsigned hi = (unsigned)f2bf(fmaf(av.z, v.z, cv.z)) |
                      ((unsigned)f2bf(fmaf(av.w, v.w, cv.w)) << 16);
        *(uint2*)&Ash[r][c] = make_uint2(lo, hi);
    }
    __syncthreads();

    int cl = l & 15, kh = l >> 4;
    f32x4 acc[8];
#pragma unroll
    for (int n = 0; n < 8; ++n) {
        float bv = b2[n * 16 + cl];
        acc[n][0] = bv; acc[n][1] = bv; acc[n][2] = bv; acc[n][3] = bv;
    }
    const unsigned short* wb = Wbf + (size_t)cl * C_H + kh * 8;
    for (int kt = 0; kt < 4; ++kt) {
        short8 af = *(const short8*)&Ash[w * 16 + cl][kt * 32 + kh * 8];
#pragma unroll
        for (int n = 0; n < 8; ++n) {
            short8 bf = *(const short8*)(wb + (size_t)n * 16 * C_H + kt * 32);
            acc[n] = __builtin_amdgcn_mfma_f32_16x16x32_bf16(af, bf, acc[n], 0, 0, 0);
        }
    }

#pragma unroll
    for (int n = 0; n < 8; ++n) {
        int col = n * 16 + cl;
        float av = a2[col], cv = c2[col];
#pragma unroll
        for (int j = 0; j < 4; ++j) {
            int row = r0 + w * 16 + kh * 4 + j;
            float z = acc[n][j];
            z = z > 0.f ? z : SLOPE * z;
            h[(size_t)row * C_H + col] = av * z + cv;
        }
    }
}

// ---------------------------------------------------------------------------
extern "C" void kernel_launch(void* const* d_in, const int* in_sizes, int n_in,
                              void* d_out, int out_size, void* d_ws, size_t ws_size,
                              hipStream_t stream) {
    const float* x          = (const float*)d_in[0];
    const float* pos        = (const float*)d_in[1];
    const float* x_skip     = (const float*)d_in[3];
    const float* pos_skip   = (const float*)d_in[4];
    const int*   batch_skip = (const int*)d_in[5];
    const float* W1  = (const float*)d_in[6];
    const float* b1  = (const float*)d_in[7];
    const float* g1  = (const float*)d_in[8];
    const float* be1 = (const float*)d_in[9];
    const float* W2  = (const float*)d_in[10];
    const float* b2  = (const float*)d_in[11];
    const float* g2  = (const float*)d_in[12];
    const float* be2 = (const float*)d_in[13];

    float* out_h     = (float*)d_out;
    float* out_pos   = out_h + (size_t)N_ROWS * C_H;
    float* out_batch = out_pos + (size_t)N_ROWS * 3;

    float* wsf = (float*)d_ws;
    float4* pos4         = (float4*)wsf;                         // 65536 floats
    unsigned short* W1bf = (unsigned short*)(wsf + 65536);       // 24576 us
    unsigned short* W2bf = (unsigned short*)(wsf + 77824);       // 16384 us
    float* p1s = wsf + 86016;                                    // 131072
    float* p1q = p1s + 131072;
    float* p2s = p1q + 131072;
    float* p2q = p2s + 131072;
    float* a1g = p2q + 131072;
    float* c1g = a1g + 128;
    float* a2g = c1g + 128;
    float* c2g = a2g + 128;

    k_prep<<<64, 256, 0, stream>>>(W1, W1bf, W2, W2bf, pos, pos4);

    void* args[] = {
        (void*)&pos4, (void*)&pos_skip, (void*)&x, (void*)&x_skip,
        (void*)&W1bf, (void*)&b1, (void*)&g1, (void*)&be1,
        (void*)&W2bf, (void*)&b2, (void*)&g2, (void*)&be2,
        (void*)&batch_skip,
        (void*)&out_h, (void*)&out_pos, (void*)&out_batch,
        (void*)&p1s, (void*)&p1q, (void*)&p2s, (void*)&p2q,
        (void*)&a1g, (void*)&c1g, (void*)&a2g, (void*)&c2g
    };
    hipError_t e = hipLaunchCooperativeKernel(k_coop, dim3(GRID_COOP), dim3(256),
                                              args, 0, stream);
    if (e != hipSuccess) {
        (void)hipGetLastError();   // clear error state; use verified split path
        k_fused1<<<GEMM_BLOCKS, 256, 0, stream>>>(pos4, pos_skip, x, x_skip,
                                                  W1bf, b1, out_h, p1s, p1q);
        k_reduce<<<C_H, 256, 0, stream>>>(p1s, p1q, g1, be1, a1g, c1g);
        k_g2a<<<GEMM_BLOCKS, 256, 0, stream>>>(out_h, W2bf, b2, a1g, c1g, p2s, p2q);
        k_reduce<<<C_H, 256, 0, stream>>>(p2s, p2q, g2, be2, a2g, c2g);
        k_g2b<<<GEMM_BLOCKS, 256, 0, stream>>>(out_h, W2bf, b2, a1g, c1g, a2g, c2g,
                                               pos_skip, batch_skip, out_pos, out_batch);
    }
}

// Round 8
// 151.223 us; speedup vs baseline: 3.6224x; 3.6224x over previous
//
#include <hip/hip_runtime.h>
#include <math.h>

#define NB 8
#define N_SRC 2048
#define N_DST 8192
#define C_SRC 128
#define C_SKIP 64
#define C_IN 192
#define C_H 128
#define N_ROWS (NB * N_DST)   /* 65536 */
#define BN_EPS 1e-5f
#define SLOPE 0.01f
#define GEMM_BLOCKS (N_ROWS / 64)   /* 1024 */

using short8 = __attribute__((ext_vector_type(8))) short;
using f32x4  = __attribute__((ext_vector_type(4))) float;

static __device__ __forceinline__ unsigned short f2bf(float f) {
    unsigned u = __builtin_bit_cast(unsigned, f);
    u = u + 0x7FFFu + ((u >> 16) & 1u);   // round-to-nearest-even
    return (unsigned short)(u >> 16);
}

// ---------------------------------------------------------------------------
// Prep: W1,W2 fp32 -> bf16 ([out][in] K-contiguous); pos -> float4 array.
// ---------------------------------------------------------------------------
__global__ __launch_bounds__(256) void k_prep(const float* __restrict__ W1,
                                              unsigned short* __restrict__ W1bf,
                                              const float* __restrict__ W2,
                                              unsigned short* __restrict__ W2bf,
                                              const float* __restrict__ pos,
                                              float4* __restrict__ pos4) {
    int gid = blockIdx.x * 256 + threadIdx.x;
    int stride = gridDim.x * 256;
    for (int i = gid; i < C_H * C_IN; i += stride) W1bf[i] = f2bf(W1[i]);
    for (int i = gid; i < C_H * C_H; i += stride)  W2bf[i] = f2bf(W2[i]);
    for (int p = gid; p < NB * N_SRC; p += stride) {
        pos4[p] = make_float4(pos[p * 3 + 0], pos[p * 3 + 1], pos[p * 3 + 2], 0.f);
    }
}

// ---------------------------------------------------------------------------
// Fused KNN + GEMM1. Block = 64 dst rows, 4 waves.
// Phase A: top-3 scan over per-wave 512-pt segment; the wave's whole segment
//          is prefetched into VGPRs (8 coalesced float4 loads/lane) and each
//          point is broadcast via v_readlane -> pure-VALU inner loop, no
//          memory ops, no waitcnt stalls.
// Phase B: merge 12 candidates; gather+interp A-tile bf16; MFMA; lrelu;
//          h1 fp32 -> out; BN1 partial sums.
// ---------------------------------------------------------------------------
__global__ __launch_bounds__(256) void k_fused1(const float4* __restrict__ pos4,
                                                const float* __restrict__ pos_skip,
                                                const float* __restrict__ x,
                                                const float* __restrict__ x_skip,
                                                const unsigned short* __restrict__ Wbf,
                                                const float* __restrict__ bias,
                                                float* __restrict__ out,
                                                float* __restrict__ ps,
                                                float* __restrict__ pq) {
    __shared__ __align__(16) unsigned short Ash[64][200];   // 25600 B (cd/ci overlay)
    __shared__ float sS[4][128];
    __shared__ float sQ[4][128];
    __shared__ int   midx[64][3];
    __shared__ float mw[64][3];

    float* cd = (float*)&Ash[0][0];                  // [4][64][3] floats
    int*   ci = (int*)((char*)&Ash[0][0] + 3072);    // [4][64][3] ints

    int tid = threadIdx.x;
    int l = tid & 63, w = tid >> 6;
    int cloud = blockIdx.x >> 7;
    int r0 = blockIdx.x * 64;

    // ---------------- Phase A: KNN scan ----------------
    int dst = r0 + l;
    float px = pos_skip[dst * 3 + 0];
    float py = pos_skip[dst * 3 + 1];
    float pz = pos_skip[dst * 3 + 2];

    // prefetch the wave's 512-point segment into VGPRs (coalesced)
    const float4* __restrict__ pw = pos4 + (cloud << 11) + (w << 9);
    float4 C[8];
#pragma unroll
    for (int c = 0; c < 8; ++c) C[c] = pw[c * 64 + l];

    float rr0 = 3.4e38f, rr1 = 3.4e38f, rr2 = 3.4e38f;
    int   ii0 = 0, ii1 = 0, ii2 = 0;
#pragma unroll
    for (int c = 0; c < 8; ++c) {
        int jb = (w << 9) + c * 64;
        int vx = __float_as_int(C[c].x);
        int vy = __float_as_int(C[c].y);
        int vz = __float_as_int(C[c].z);
#pragma unroll 16
        for (int k = 0; k < 64; ++k) {
            float sx = __int_as_float(__builtin_amdgcn_readlane(vx, k));
            float sy = __int_as_float(__builtin_amdgcn_readlane(vy, k));
            float sz = __int_as_float(__builtin_amdgcn_readlane(vz, k));
            float dx = px - sx, dy = py - sy, dz = pz - sz;
            float d = fmaf(dx, dx, fmaf(dy, dy, dz * dz));
            if (d < rr2) {                      // rarely taken
                int jj = jb + k;
                bool c0 = d < rr0, c1 = d < rr1;
                ii2 = c1 ? ii1 : jj;              rr2 = c1 ? rr1 : d;
                ii1 = c1 ? (c0 ? ii0 : jj) : ii1; rr1 = c1 ? (c0 ? rr0 : d) : rr1;
                ii0 = c0 ? jj : ii0;              rr0 = c0 ? d : rr0;
            }
        }
    }
    cd[(w * 64 + l) * 3 + 0] = rr0; ci[(w * 64 + l) * 3 + 0] = ii0;
    cd[(w * 64 + l) * 3 + 1] = rr1; ci[(w * 64 + l) * 3 + 1] = ii1;
    cd[(w * 64 + l) * 3 + 2] = rr2; ci[(w * 64 + l) * 3 + 2] = ii2;
    __syncthreads();

    // ---------------- merge 12 candidates per dst ----------------
    if (tid < 64) {
        float e0 = 3.4e38f, e1 = 3.4e38f, e2 = 3.4e38f;
        int   m0 = 0, m1 = 0, m2 = 0;
#pragma unroll
        for (int s = 0; s < 4; ++s) {
#pragma unroll
            for (int t = 0; t < 3; ++t) {
                float d = cd[(s * 64 + tid) * 3 + t];
                int  jj = ci[(s * 64 + tid) * 3 + t];
                if (d < e2) {
                    bool c0 = d < e0, c1 = d < e1;
                    m2 = c1 ? m1 : jj;            e2 = c1 ? e1 : d;
                    m1 = c1 ? (c0 ? m0 : jj) : m1; e1 = c1 ? (c0 ? e0 : d) : e1;
                    m0 = c0 ? jj : m0;            e0 = c0 ? d : e0;
                }
            }
        }
        float w0 = 1.f / fmaxf(e0, 1e-16f);
        float w1 = 1.f / fmaxf(e1, 1e-16f);
        float w2 = 1.f / fmaxf(e2, 1e-16f);
        float inv = 1.f / (w0 + w1 + w2);
        midx[tid][0] = m0; midx[tid][1] = m1; midx[tid][2] = m2;
        mw[tid][0] = w0 * inv; mw[tid][1] = w1 * inv; mw[tid][2] = w2 * inv;
    }
    __syncthreads();

    // ---------------- Phase B: gather + interp -> bf16 A tile ----------------
    const float* xb = x + (size_t)cloud * N_SRC * C_SRC;
    for (int rr = w * 16; rr < w * 16 + 16; ++rr) {
        int j0 = midx[rr][0], j1 = midx[rr][1], j2 = midx[rr][2];
        float w0 = mw[rr][0], w1 = mw[rr][1], w2 = mw[rr][2];
        const float2* x0v = (const float2*)(xb + (size_t)j0 * C_SRC);
        const float2* x1v = (const float2*)(xb + (size_t)j1 * C_SRC);
        const float2* x2v = (const float2*)(xb + (size_t)j2 * C_SRC);
        float2 a = x0v[l], b = x1v[l], c = x2v[l];
        float v0 = w0 * a.x + w1 * b.x + w2 * c.x;
        float v1 = w0 * a.y + w1 * b.y + w2 * c.y;
        ((unsigned*)&Ash[rr][0])[l] = (unsigned)f2bf(v0) | ((unsigned)f2bf(v1) << 16);
        Ash[rr][128 + l] = f2bf(x_skip[(size_t)(r0 + rr) * C_SKIP + l]);
    }
    // waves read only their own 16-row slab -> no barrier needed

    // ---------------- MFMA ----------------
    int cl = l & 15, kh = l >> 4;
    f32x4 acc[8];
#pragma unroll
    for (int n = 0; n < 8; ++n) {
        float bv = bias[n * 16 + cl];
        acc[n][0] = bv; acc[n][1] = bv; acc[n][2] = bv; acc[n][3] = bv;
    }
    const unsigned short* wb = Wbf + (size_t)cl * C_IN + kh * 8;
    for (int kt = 0; kt < 6; ++kt) {
        short8 af = *(const short8*)&Ash[w * 16 + cl][kt * 32 + kh * 8];
#pragma unroll
        for (int n = 0; n < 8; ++n) {
            short8 bf = *(const short8*)(wb + (size_t)n * 16 * C_IN + kt * 32);
            acc[n] = __builtin_amdgcn_mfma_f32_16x16x32_bf16(af, bf, acc[n], 0, 0, 0);
        }
    }

    // ---------------- epilogue: lrelu + store fp32 + BN1 partials ----------------
    float pss[8], pqs[8];
#pragma unroll
    for (int n = 0; n < 8; ++n) {
        float s = 0.f, q = 0.f;
        int col = n * 16 + cl;
#pragma unroll
        for (int j = 0; j < 4; ++j) {
            int row = r0 + w * 16 + kh * 4 + j;
            float z = acc[n][j];
            z = z > 0.f ? z : SLOPE * z;
            out[(size_t)row * C_H + col] = z;
            s += z; q += z * z;
        }
        s += __shfl_xor(s, 16); s += __shfl_xor(s, 32);
        q += __shfl_xor(q, 16); q += __shfl_xor(q, 32);
        pss[n] = s; pqs[n] = q;
    }
    if (l < 16) {
#pragma unroll
        for (int n = 0; n < 8; ++n) {
            sS[w][n * 16 + l] = pss[n];
            sQ[w][n * 16 + l] = pqs[n];
        }
    }
    __syncthreads();
    if (tid < 128) {
        float s = sS[0][tid] + sS[1][tid] + sS[2][tid] + sS[3][tid];
        float q = sQ[0][tid] + sQ[1][tid] + sQ[2][tid] + sQ[3][tid];
        ps[blockIdx.x * C_H + tid] = s;
        pq[blockIdx.x * C_H + tid] = q;
    }
}

// ---------------------------------------------------------------------------
// Per-channel reduce of block partials -> BN affine
// ---------------------------------------------------------------------------
__global__ __launch_bounds__(256) void k_reduce(const float* __restrict__ ps,
                                                const float* __restrict__ pq,
                                                const float* __restrict__ g,
                                                const float* __restrict__ be,
                                                float* __restrict__ a_out,
                                                float* __restrict__ c_out) {
    int col = blockIdx.x;
    float s = 0.f, q = 0.f;
    for (int b = threadIdx.x; b < GEMM_BLOCKS; b += 256) {
        s += ps[b * C_H + col];
        q += pq[b * C_H + col];
    }
    for (int off = 32; off; off >>= 1) {
        s += __shfl_down(s, off);
        q += __shfl_down(q, off);
    }
    __shared__ float rs[4], rq[4];
    if ((threadIdx.x & 63) == 0) { rs[threadIdx.x >> 6] = s; rq[threadIdx.x >> 6] = q; }
    __syncthreads();
    if (threadIdx.x == 0) {
        s = rs[0] + rs[1] + rs[2] + rs[3];
        q = rq[0] + rq[1] + rq[2] + rq[3];
        float mean = s / (float)N_ROWS;
        float var  = q / (float)N_ROWS - mean * mean;
        float a = g[col] * rsqrtf(var + BN_EPS);
        a_out[col] = a;
        c_out[col] = be[col] - mean * a;
    }
}

// ---------------------------------------------------------------------------
// GEMM2a: stats-only pass. Stage Ash = bf16(a1*h1 + c1) (BN1 applied here);
// z2 = Ash@W2bf^T + b2; lrelu; BN2 partials. No store.
// ---------------------------------------------------------------------------
__global__ __launch_bounds__(256) void k_g2a(const float* __restrict__ h,
                                             const unsigned short* __restrict__ Wbf,
                                             const float* __restrict__ b2,
                                             const float* __restrict__ a1,
                                             const float* __restrict__ c1,
                                             float* __restrict__ ps,
                                             float* __restrict__ pq) {
    __shared__ __align__(16) unsigned short Ash[64][136];
    __shared__ float sS[4][128];
    __shared__ float sQ[4][128];

    int r0 = blockIdx.x * 64;
    int tid = threadIdx.x;
    int l = tid & 63, w = tid >> 6;

    const float* src = h + (size_t)r0 * C_H;
    for (int i = tid * 4; i < 64 * C_H; i += 1024) {
        float4 v = *(const float4*)&src[i];
        int r = i >> 7, c = i & 127;
        float4 av = *(const float4*)&a1[c];
        float4 cv = *(const float4*)&c1[c];
        unsigned lo = (unsigned)f2bf(fmaf(av.x, v.x, cv.x)) |
                      ((unsigned)f2bf(fmaf(av.y, v.y, cv.y)) << 16);
        unsigned hi = (unsigned)f2bf(fmaf(av.z, v.z, cv.z)) |
                      ((unsigned)f2bf(fmaf(av.w, v.w, cv.w)) << 16);
        *(uint2*)&Ash[r][c] = make_uint2(lo, hi);
    }
    __syncthreads();

    int cl = l & 15, kh = l >> 4;
    f32x4 acc[8];
#pragma unroll
    for (int n = 0; n < 8; ++n) {
        float bv = b2[n * 16 + cl];
        acc[n][0] = bv; acc[n][1] = bv; acc[n][2] = bv; acc[n][3] = bv;
    }
    const unsigned short* wb = Wbf + (size_t)cl * C_H + kh * 8;
    for (int kt = 0; kt < 4; ++kt) {
        short8 af = *(const short8*)&Ash[w * 16 + cl][kt * 32 + kh * 8];
#pragma unroll
        for (int n = 0; n < 8; ++n) {
            short8 bf = *(const short8*)(wb + (size_t)n * 16 * C_H + kt * 32);
            acc[n] = __builtin_amdgcn_mfma_f32_16x16x32_bf16(af, bf, acc[n], 0, 0, 0);
        }
    }

    float pss[8], pqs[8];
#pragma unroll
    for (int n = 0; n < 8; ++n) {
        float s = 0.f, q = 0.f;
#pragma unroll
        for (int j = 0; j < 4; ++j) {
            float z = acc[n][j];
            z = z > 0.f ? z : SLOPE * z;
            s += z; q += z * z;
        }
        s += __shfl_xor(s, 16); s += __shfl_xor(s, 32);
        q += __shfl_xor(q, 16); q += __shfl_xor(q, 32);
        pss[n] = s; pqs[n] = q;
    }
    if (l < 16) {
#pragma unroll
        for (int n = 0; n < 8; ++n) {
            sS[w][n * 16 + l] = pss[n];
            sQ[w][n * 16 + l] = pqs[n];
        }
    }
    __syncthreads();
    if (tid < 128) {
        float s = sS[0][tid] + sS[1][tid] + sS[2][tid] + sS[3][tid];
        float q = sQ[0][tid] + sQ[1][tid] + sQ[2][tid] + sQ[3][tid];
        ps[blockIdx.x * C_H + tid] = s;
        pq[blockIdx.x * C_H + tid] = q;
    }
}

// ---------------------------------------------------------------------------
// GEMM2b: recompute z2 (same staging), lrelu + BN2 affine, write d_out in
// place (block reads only its own 64 rows -> race-free). Copies pos/batch.
// ---------------------------------------------------------------------------
__global__ __launch_bounds__(256) void k_g2b(float* __restrict__ h,
                                             const unsigned short* __restrict__ Wbf,
                                             const float* __restrict__ b2,
                                             const float* __restrict__ a1,
                                             const float* __restrict__ c1,
                                             const float* __restrict__ a2,
                                             const float* __restrict__ c2,
                                             const float* __restrict__ pos_skip,
                                             const int* __restrict__ batch_skip,
                                             float* __restrict__ out_pos,
                                             float* __restrict__ out_batch) {
    __shared__ __align__(16) unsigned short Ash[64][136];

    int r0 = blockIdx.x * 64;
    int tid = threadIdx.x;
    int l = tid & 63, w = tid >> 6;

    if (tid < 192) out_pos[(size_t)r0 * 3 + tid] = pos_skip[(size_t)r0 * 3 + tid];
    if (tid < 64)  out_batch[r0 + tid] = (float)batch_skip[r0 + tid];

    const float* src = h + (size_t)r0 * C_H;
    for (int i = tid * 4; i < 64 * C_H; i += 1024) {
        float4 v = *(const float4*)&src[i];
        int r = i >> 7, c = i & 127;
        float4 av = *(const float4*)&a1[c];
        float4 cv = *(const float4*)&c1[c];
        unsigned lo = (unsigned)f2bf(fmaf(av.x, v.x, cv.x)) |
                      ((unsigned)f2bf(fmaf(av.y, v.y, cv.y)) << 16);
        unsigned hi = (unsigned)f2bf(fmaf(av.z, v.z, cv.z)) |
                      ((unsigned)f2bf(fmaf(av.w, v.w, cv.w)) << 16);
        *(uint2*)&Ash[r][c] = make_uint2(lo, hi);
    }
    __syncthreads();

    int cl = l & 15, kh = l >> 4;
    f32x4 acc[8];
#pragma unroll
    for (int n = 0; n < 8; ++n) {
        float bv = b2[n * 16 + cl];
        acc[n][0] = bv; acc[n][1] = bv; acc[n][2] = bv; acc[n][3] = bv;
    }
    const unsigned short* wb = Wbf + (size_t)cl * C_H + kh * 8;
    for (int kt = 0; kt < 4; ++kt) {
        short8 af = *(const short8*)&Ash[w * 16 + cl][kt * 32 + kh * 8];
#pragma unroll
        for (int n = 0; n < 8; ++n) {
            short8 bf = *(const short8*)(wb + (size_t)n * 16 * C_H + kt * 32);
            acc[n] = __builtin_amdgcn_mfma_f32_16x16x32_bf16(af, bf, acc[n], 0, 0, 0);
        }
    }

#pragma unroll
    for (int n = 0; n < 8; ++n) {
        int col = n * 16 + cl;
        float av = a2[col], cv = c2[col];
#pragma unroll
        for (int j = 0; j < 4; ++j) {
            int row = r0 + w * 16 + kh * 4 + j;
            float z = acc[n][j];
            z = z > 0.f ? z : SLOPE * z;
            h[(size_t)row * C_H + col] = av * z + cv;
        }
    }
}

// ---------------------------------------------------------------------------
extern "C" void kernel_launch(void* const* d_in, const int* in_sizes, int n_in,
                              void* d_out, int out_size, void* d_ws, size_t ws_size,
                              hipStream_t stream) {
    const float* x          = (const float*)d_in[0];
    const float* pos        = (const float*)d_in[1];
    const float* x_skip     = (const float*)d_in[3];
    const float* pos_skip   = (const float*)d_in[4];
    const int*   batch_skip = (const int*)d_in[5];
    const float* W1  = (const float*)d_in[6];
    const float* b1  = (const float*)d_in[7];
    const float* g1  = (const float*)d_in[8];
    const float* be1 = (const float*)d_in[9];
    const float* W2  = (const float*)d_in[10];
    const float* b2  = (const float*)d_in[11];
    const float* g2  = (const float*)d_in[12];
    const float* be2 = (const float*)d_in[13];

    float* out_h     = (float*)d_out;
    float* out_pos   = out_h + (size_t)N_ROWS * C_H;
    float* out_batch = out_pos + (size_t)N_ROWS * 3;

    float* wsf = (float*)d_ws;
    float4* pos4         = (float4*)wsf;                         // 65536 floats
    unsigned short* W1bf = (unsigned short*)(wsf + 65536);       // 24576 us
    unsigned short* W2bf = (unsigned short*)(wsf + 77824);       // 16384 us
    float* p1s = wsf + 86016;                                    // 131072
    float* p1q = p1s + 131072;
    float* p2s = p1q + 131072;
    float* p2q = p2s + 131072;
    float* a1g = p2q + 131072;
    float* c1g = a1g + 128;
    float* a2g = c1g + 128;
    float* c2g = a2g + 128;

    k_prep<<<64, 256, 0, stream>>>(W1, W1bf, W2, W2bf, pos, pos4);
    k_fused1<<<GEMM_BLOCKS, 256, 0, stream>>>(pos4, pos_skip, x, x_skip, W1bf, b1,
                                              out_h, p1s, p1q);
    k_reduce<<<C_H, 256, 0, stream>>>(p1s, p1q, g1, be1, a1g, c1g);
    k_g2a<<<GEMM_BLOCKS, 256, 0, stream>>>(out_h, W2bf, b2, a1g, c1g, p2s, p2q);
    k_reduce<<<C_H, 256, 0, stream>>>(p2s, p2q, g2, be2, a2g, c2g);
    k_g2b<<<GEMM_BLOCKS, 256, 0, stream>>>(out_h, W2bf, b2, a1g, c1g, a2g, c2g,
                                           pos_skip, batch_skip, out_pos, out_batch);
}